// Round 10
// baseline (57.088 us; speedup 1.0000x reference)
//
#include <hip/hip_runtime.h>

typedef __attribute__((ext_vector_type(8))) short bf16x8;
typedef __attribute__((ext_vector_type(4))) float f32x4;

#define B_    2048
#define S_    512

// ws layout (bytes)
#define OFF_WF1   0u          // Wfrag1[32 nt][4 ks][64 lane][8] bf16 = 131072
#define OFF_WF2   131072u     // Wfrag2[32][16][64][8] = 524288
#define OFF_WF3   655360u     // Wfrag3[32][16][64][8] = 524288
#define OFF_WFF   1179648u    // WfragF[16 ks][64][8]  = 16384 (cols>=2 zero)
#define OFF_PREF  1196032u    // float pref[512][64] (50 used) = 131072
#define OFF_POOLG 1327104u    // bf16 pooled [2048][128] = 524288
#define OFF_EMBB  1851392u    // bf16 emb [50000][64] (one 128B line per row)
#define WS_NEED   (OFF_EMBB + 6400000u)

__device__ __forceinline__ unsigned short f2bf(float f) {
    unsigned int u = __float_as_uint(f);
    u += 0x7FFFu + ((u >> 16) & 1u);          // round-to-nearest-even
    return (unsigned short)(u >> 16);
}

#define MFMA16(a, b, c) __builtin_amdgcn_mfma_f32_16x16x32_bf16((a), (b), (c), 0, 0, 0)

// ---------------- prep_convert: weights->fragment-order bf16, pos-prefix, emb
// (unchanged from round 9)
__global__ __launch_bounds__(256) void prep_convert(
    const float* __restrict__ W1, const float* __restrict__ W2,
    const float* __restrict__ W3, const float* __restrict__ Wf,
    const float* __restrict__ post, const int* __restrict__ pos,
    const float* __restrict__ emb,
    unsigned short* __restrict__ ws, float* __restrict__ pref, int do_emb)
{
    const int bid = blockIdx.x;
    const int tid = threadIdx.x;

    if (bid < 152) {                      // ---- weight convert, 64x64 (k,n) tile
        __shared__ float tile[64][65];
        const float* src; unsigned short* dst;
        int k0, n0, Ksrc, Nsrc, ksTot, nTiles;
        if (bid < 64)       { src=W2; dst=ws+OFF_WF2/2; k0=(bid>>3)*64; n0=(bid&7)*64; Ksrc=512; Nsrc=512; ksTot=16; nTiles=4; }
        else if (bid < 128) { int b=bid-64;  src=W3; dst=ws+OFF_WF3/2; k0=(b>>3)*64; n0=(b&7)*64; Ksrc=512; Nsrc=512; ksTot=16; nTiles=4; }
        else if (bid < 144) { int b=bid-128; src=W1; dst=ws+OFF_WF1/2; k0=(b>>3)*64; n0=(b&7)*64; Ksrc=100; Nsrc=512; ksTot=4;  nTiles=4; }
        else                { int b=bid-144; src=Wf; dst=ws+OFF_WFF/2; k0=b*64;      n0=0;        Ksrc=512; Nsrc=2;   ksTot=16; nTiles=1; }

        const int c  = tid & 63;
        const int r4 = tid >> 6;
#pragma unroll
        for (int rr = 0; rr < 16; ++rr) {
            int r = rr*4 + r4;
            float v = 0.f;
            if (k0 + r < Ksrc && n0 + c < Nsrc) v = src[(size_t)(k0+r)*Nsrc + n0 + c];
            tile[r][c] = v;
        }
        __syncthreads();
        const int nWords = nTiles * 2 * 64;
        for (int w = tid; w < nWords; w += 256) {
            int lane = w & 63, ks_l = (w >> 6) & 1, nt_l = w >> 7;
            int kr = ks_l*32 + ((lane >> 4) << 3);
            int nc = nt_l*16 + (lane & 15);
            uint4 wv;
            wv.x = (unsigned)f2bf(tile[kr+0][nc]) | ((unsigned)f2bf(tile[kr+1][nc]) << 16);
            wv.y = (unsigned)f2bf(tile[kr+2][nc]) | ((unsigned)f2bf(tile[kr+3][nc]) << 16);
            wv.z = (unsigned)f2bf(tile[kr+4][nc]) | ((unsigned)f2bf(tile[kr+5][nc]) << 16);
            wv.w = (unsigned)f2bf(tile[kr+6][nc]) | ((unsigned)f2bf(tile[kr+7][nc]) << 16);
            int ntile = (n0 >> 4) + nt_l, ks = (k0 >> 5) + ks_l;
            ((uint4*)dst)[(size_t)(ntile*ksTot + ks)*64 + lane] = wv;
        }
    } else if (bid == 152) {              // ---- pos-prefix, 4 chunks x 128, batch-8
        __shared__ int   idx_s[512];
        __shared__ float csum[4][52];
        idx_s[tid]       = pos[tid];
        idx_s[tid + 256] = pos[tid + 256];
        __syncthreads();
        const int c = tid >> 6, d = tid & 63;
        if (d < 50) {
            float run = 0.f;
            for (int b8 = 0; b8 < 16; ++b8) {
                float t[8];
#pragma unroll
                for (int u = 0; u < 8; ++u)
                    t[u] = post[(size_t)idx_s[c*128 + b8*8 + u]*50 + d];
#pragma unroll
                for (int u = 0; u < 8; ++u) {
                    run += t[u];
                    pref[(size_t)(c*128 + b8*8 + u)*64 + d] = run;
                }
            }
            csum[c][d] = run;
        }
        __syncthreads();
        if (d < 50 && c > 0) {
            float off = 0.f;
            for (int cc = 0; cc < c; ++cc) off += csum[cc][d];
            for (int b8 = 0; b8 < 16; ++b8) {
                float t[8];
#pragma unroll
                for (int u = 0; u < 8; ++u)
                    t[u] = pref[(size_t)(c*128 + b8*8 + u)*64 + d];
#pragma unroll
                for (int u = 0; u < 8; ++u)
                    pref[(size_t)(c*128 + b8*8 + u)*64 + d] = t[u] + off;
            }
        }
    } else {                              // ---- emb fp32 -> bf16, coalesced float2, ILP-8
        if (!do_emb) return;
        unsigned* embw = (unsigned*)(ws + OFF_EMBB/2);
        const float2* e2 = (const float2*)emb;        // 1,250,000 float2; never crosses a row
        const unsigned q0 = (unsigned)(bid - 153) * 2048u + (unsigned)tid;
        float2 v[8];
#pragma unroll
        for (int u = 0; u < 8; ++u) {
            unsigned q = q0 + (unsigned)u*256u;
            v[u] = (q < 1250000u) ? e2[q] : (float2){0.f, 0.f};
        }
#pragma unroll
        for (int u = 0; u < 8; ++u) {
            unsigned q = q0 + (unsigned)u*256u;
            if (q < 1250000u) {
                unsigned r = q / 25u, c2 = q - r*25u;
                embw[(size_t)r*32u + c2] =
                    (unsigned)f2bf(v[u].x) | ((unsigned)f2bf(v[u].y) << 16);
            }
        }
    }
}

// ---------------- pool_kernel: masked-mean gather, deep-pipelined -------------
// 512 blocks x 256 thr; wave = one batch row. 8 lanes per token (one 128B line,
// fully consumed); explicit 4-deep rotation (named q0..q3) keeps ~32 lines in
// flight per wave. Butterfly reduce; lane<16 stores one bf16x8 word of the
// [2048][128] pooled row (emb sums | pos prefix | zero pad).
__device__ __forceinline__ void acc_uint4(float (&a)[8], uint4 q) {
    unsigned dw[4] = {q.x, q.y, q.z, q.w};
#pragma unroll
    for (int v = 0; v < 4; ++v) {
        a[2*v]   += __uint_as_float(dw[v] << 16);
        a[2*v+1] += __uint_as_float(dw[v] & 0xffff0000u);
    }
}

#define LOADQ(qv, bidx) { int s_ = (bidx)*8 + tg; qv = (uint4){0u,0u,0u,0u}; \
    if (s_ < L) qv = tbl[(size_t)idxr[s_]*8u + (unsigned)dq]; }

template<int EMODE>
__global__ __launch_bounds__(256) void pool_kernel(
    const float* __restrict__ emb, const int* __restrict__ seq,
    const int* __restrict__ seqlen, const unsigned short* __restrict__ ws_ro,
    const float* __restrict__ pref, unsigned short* __restrict__ pooled_g)
{
    __shared__ unsigned short idx_s[4*512];
    const int tid = threadIdx.x, wave = tid >> 6, lane = tid & 63;
    const int b0 = blockIdx.x * 4;
    for (int i = tid; i < 4*512; i += 256)
        idx_s[i] = (unsigned short)seq[(size_t)b0 * S_ + i];
    __syncthreads();

    const int row = b0 + wave;
    const int L = seqlen[row];
    const float invL = 1.f / (float)L;
    const unsigned short* idxr = idx_s + wave*512;

    if (EMODE == 0) {
        const int tg = lane >> 3, dq = lane & 7;
        const uint4* tbl = (const uint4*)(ws_ro + OFF_EMBB/2);
        float acc8[8] = {0.f,0.f,0.f,0.f,0.f,0.f,0.f,0.f};
        uint4 q0, q1, q2, q3;
        LOADQ(q0, 0) LOADQ(q1, 1) LOADQ(q2, 2) LOADQ(q3, 3)
        const int nbr = (L + 7) >> 3;             // 8-token batches
        for (int i = 0; i < nbr; i += 4) {
            acc_uint4(acc8, q0); LOADQ(q0, i+4)
            acc_uint4(acc8, q1); LOADQ(q1, i+5)
            acc_uint4(acc8, q2); LOADQ(q2, i+6)
            acc_uint4(acc8, q3); LOADQ(q3, i+7)
        }
#pragma unroll
        for (int j = 0; j < 8; ++j) acc8[j] += __shfl_xor(acc8[j], 8);
#pragma unroll
        for (int j = 0; j < 8; ++j) acc8[j] += __shfl_xor(acc8[j], 16);
#pragma unroll
        for (int j = 0; j < 8; ++j) acc8[j] += __shfl_xor(acc8[j], 32);
        // lane l holds emb-sums for dims (l&7)*8 + j; lanes 0..6 use them directly
        if (lane < 16) {
            const float* prow = pref + (size_t)(L-1)*64;
            unsigned short w8[8];
#pragma unroll
            for (int j = 0; j < 8; ++j) {
                int d = lane*8 + j;
                float v;
                if (d < 50)       v = acc8[j] * invL;
                else if (d < 100) v = prow[d - 50] * invL;
                else              v = 0.f;
                w8[j] = f2bf(v);
            }
            bf16x8 wv;
#pragma unroll
            for (int j = 0; j < 8; ++j) wv[j] = (short)w8[j];
            ((bf16x8*)pooled_g)[(size_t)row*16 + lane] = wv;
        }
    } else {
        float accE = 0.f;
        for (int s = 0; s < L; ++s) {
            int tok = idxr[s];
            if (lane < 50) accE += emb[(size_t)tok*50 + lane];
        }
        if (lane < 50)  pooled_g[(size_t)row*128 + lane] = f2bf(accE * invL);
        else if (lane < 64) pooled_g[(size_t)row*128 + lane + 64] = 0;
        if (lane < 50)
            pooled_g[(size_t)row*128 + 50 + lane] =
                f2bf(pref[(size_t)(L-1)*64 + lane] * invL);
        else if (lane < 64)
            pooled_g[(size_t)row*128 + (lane - 50 >= 0 ? 0 : 0) + 100 + (lane - 50)] = 0;
        // note: fallback path writes dims 0..49, 50..99, and zeros 100..127 via the
        // two else-branches above (lanes 50..63 cover 114..127 and 100..113).
    }
}

// ---------------- MFMA helpers (swizzled LDS h-tiles, verified r2-r9) --------
__device__ __forceinline__ void load_afrags(bf16x8 (&a)[16],
    const unsigned short* h, int row, int kq)
{
#pragma unroll
    for (int ks = 0; ks < 16; ++ks)
        a[ks] = *(const bf16x8*)((const char*)h +
                  (((unsigned)(row * 1024 + ks * 64 + kq * 16)) ^ ((row & 7) << 4)));
}

__device__ __forceinline__ void store_h(unsigned short* h, const f32x4 (&acc)[4],
    const float (&bb)[4], int wave, int row, int kq)
{
#pragma unroll
    for (int nt = 0; nt < 4; ++nt) {
        int c = wave*64 + nt*16 + row;
#pragma unroll
        for (int r4 = 0; r4 < 4; ++r4) {
            int hrow = kq*4 + r4;
            unsigned base = hrow * 1024;
            *(unsigned short*)((char*)h + ((base + c*2) ^ ((hrow & 7) << 4))) =
                f2bf(fmaxf(acc[nt][r4] + bb[nt], 0.f));
        }
    }
}

__device__ __forceinline__ void layer512(
    const bf16x8 (&a)[16], const unsigned short* __restrict__ Wfrag,
    const float* __restrict__ bias, unsigned short* hout,
    int wave, int row, int kq, int lane)
{
    const bf16x8* bp = (const bf16x8*)Wfrag + ((size_t)(wave*4) * 16 * 64) + lane;
    float bb[4];
#pragma unroll
    for (int nt = 0; nt < 4; ++nt) bb[nt] = bias[wave*64 + nt*16 + row];

    bf16x8 bvA[16], bvB[16];
#pragma unroll
    for (int ks = 0; ks < 16; ++ks) bvA[ks] = bp[(0*16 + ks)*64];
#pragma unroll
    for (int ks = 0; ks < 16; ++ks) bvB[ks] = bp[(1*16 + ks)*64];

    f32x4 acc[4];
    acc[0] = (f32x4){0.f,0.f,0.f,0.f};
#pragma unroll
    for (int ks = 0; ks < 16; ++ks) acc[0] = MFMA16(a[ks], bvA[ks], acc[0]);
#pragma unroll
    for (int ks = 0; ks < 16; ++ks) bvA[ks] = bp[(2*16 + ks)*64];

    acc[1] = (f32x4){0.f,0.f,0.f,0.f};
#pragma unroll
    for (int ks = 0; ks < 16; ++ks) acc[1] = MFMA16(a[ks], bvB[ks], acc[1]);
#pragma unroll
    for (int ks = 0; ks < 16; ++ks) bvB[ks] = bp[(3*16 + ks)*64];

    acc[2] = (f32x4){0.f,0.f,0.f,0.f};
#pragma unroll
    for (int ks = 0; ks < 16; ++ks) acc[2] = MFMA16(a[ks], bvA[ks], acc[2]);
    acc[3] = (f32x4){0.f,0.f,0.f,0.f};
#pragma unroll
    for (int ks = 0; ks < 16; ++ks) acc[3] = MFMA16(a[ks], bvB[ks], acc[3]);

    store_h(hout, acc, bb, wave, row, kq);
}

// ---------------- dan_mlp: 4-layer MFMA MLP (r6-verified, pooling external) --
__global__ __launch_bounds__(512, 2) void dan_mlp(
    const unsigned short* __restrict__ ws_ro,
    const float* __restrict__ b1, const float* __restrict__ b2,
    const float* __restrict__ b3, const float* __restrict__ bfin,
    float* __restrict__ out)
{
    __shared__ __align__(16) unsigned short pooled_s[16*144]; // 4.6 KB
    __shared__ __align__(16) unsigned short hA[8192];         // 16 KB
    __shared__ __align__(16) unsigned short hB[8192];         // 16 KB

    const int tid  = threadIdx.x;
    const int wave = tid >> 6;
    const int lane = tid & 63;
    const int row  = lane & 15;
    const int kq   = lane >> 4;
    const int b0   = blockIdx.x * 8;

    const unsigned short* WF1 = ws_ro + OFF_WF1 / 2;
    const unsigned short* WF2 = ws_ro + OFF_WF2 / 2;
    const unsigned short* WF3 = ws_ro + OFF_WF3 / 2;
    const unsigned short* WFF = ws_ro + OFF_WFF / 2;
    const unsigned short* pooled_g = ws_ro + OFF_POOLG / 2;

    // W1 fragments: 16 coalesced 16B loads per wave
    bf16x8 w1f[4][4];
    {
        const bf16x8* bp1 = (const bf16x8*)WF1 + ((size_t)(wave*4) * 4 * 64) + lane;
#pragma unroll
        for (int ci = 0; ci < 4; ++ci)
#pragma unroll
            for (int ks = 0; ks < 4; ++ks) w1f[ci][ks] = bp1[(ci*4 + ks)*64];
    }

    // stage pooled rows b0..b0+7 into [16][144] LDS (rows 8-15 zero)
    for (int i = tid; i < 16*144; i += 512) {
        int r = i / 144, c = i - r*144;
        unsigned short v = 0;
        if (r < 8 && c < 128) v = pooled_g[(size_t)(b0 + r)*128 + c];
        pooled_s[i] = v;
    }
    __syncthreads();

    // ---- Layer 1 (K=128) from pooled_s, weights in regs
    {
        bf16x8 a1[4];
#pragma unroll
        for (int ks = 0; ks < 4; ++ks)
            a1[ks] = *(const bf16x8*)&pooled_s[row*144 + ks*32 + kq*8];
        f32x4 acc[4];
        float bb[4];
#pragma unroll
        for (int ci = 0; ci < 4; ++ci) {
            bb[ci] = b1[wave*64 + ci*16 + row];
            acc[ci] = (f32x4){0.f,0.f,0.f,0.f};
#pragma unroll
            for (int ks = 0; ks < 4; ++ks) acc[ci] = MFMA16(a1[ks], w1f[ci][ks], acc[ci]);
        }
        store_h(hA, acc, bb, wave, row, kq);
    }
    __syncthreads();

    // ---- Layer 2 (K=512): hA -> hB
    bf16x8 a[16];
    load_afrags(a, hA, row, kq);
    layer512(a, WF2, b2, hB, wave, row, kq, lane);
    __syncthreads();

    // ---- Layer 3 (K=512): hB -> hA
    load_afrags(a, hB, row, kq);
    layer512(a, WF3, b3, hA, wave, row, kq, lane);
    __syncthreads();

    // ---- Final (K=512, N padded 2->16): wave 0 only
    if (wave == 0) {
        load_afrags(a, hA, row, kq);
        const bf16x8* bpf = (const bf16x8*)WFF + lane;
        f32x4 accf = {0.f, 0.f, 0.f, 0.f};
#pragma unroll
        for (int ks = 0; ks < 16; ++ks) {
            bf16x8 bv = bpf[ks*64];
            accf = MFMA16(a[ks], bv, accf);
        }
        if (row < 2 && kq < 2) {
            float bb = bfin[row];
#pragma unroll
            for (int r4 = 0; r4 < 4; ++r4) {
                int m = kq*4 + r4;                   // real rows 0..7
                out[(size_t)(b0 + m) * 2 + row] = accf[r4] + bb;
            }
        }
    }
}

extern "C" void kernel_launch(void* const* d_in, const int* in_sizes, int n_in,
                              void* d_out, int out_size, void* d_ws, size_t ws_size,
                              hipStream_t stream)
{
    const float* emb    = (const float*)d_in[0];
    const float* post   = (const float*)d_in[1];
    const float* W1     = (const float*)d_in[2];
    const float* b1     = (const float*)d_in[3];
    const float* W2     = (const float*)d_in[4];
    const float* b2     = (const float*)d_in[5];
    const float* W3     = (const float*)d_in[6];
    const float* b3     = (const float*)d_in[7];
    const float* Wf     = (const float*)d_in[8];
    const float* bf     = (const float*)d_in[9];
    const int*   seq    = (const int*)d_in[10];
    const int*   seqlen = (const int*)d_in[11];
    const int*   pos    = (const int*)d_in[12];
    float*       out    = (float*)d_out;

    unsigned short* ws = (unsigned short*)d_ws;
    float* pref = (float*)((char*)d_ws + OFF_PREF);
    unsigned short* pooled_g = ws + OFF_POOLG/2;
    const int do_emb = (ws_size >= (size_t)WS_NEED) ? 1 : 0;

    const int prep_blocks = do_emb ? (153 + 611) : 153;
    prep_convert<<<prep_blocks, 256, 0, stream>>>(W1, W2, W3, Wf, post, pos, emb,
                                                  ws, pref, do_emb);
    if (do_emb)
        pool_kernel<0><<<512, 256, 0, stream>>>(emb, seq, seqlen, ws, pref, pooled_g);
    else
        pool_kernel<1><<<512, 256, 0, stream>>>(emb, seq, seqlen, ws, pref, pooled_g);
    dan_mlp<<<B_ / 8, 512, 0, stream>>>(ws, b1, b2, b3, bf, out);
}

// Round 12
// 45.524 us; speedup vs baseline: 1.2540x; 1.2540x over previous
//
#include <hip/hip_runtime.h>

typedef __attribute__((ext_vector_type(8))) short bf16x8;
typedef __attribute__((ext_vector_type(4))) float f32x4;
typedef __attribute__((ext_vector_type(4))) unsigned u32x4;

#define B_    2048
#define S_    512

// ws layout (bytes)
#define OFF_WF1   0u          // Wfrag1[32 nt][4 ks][64 lane][8] bf16 = 131072
#define OFF_WF2   131072u     // Wfrag2[32][16][64][8] = 524288
#define OFF_WF3   655360u     // Wfrag3[32][16][64][8] = 524288
#define OFF_WFF   1179648u    // WfragF[16 ks][64][8]  = 16384 (cols>=2 zero)
#define OFF_PREF  1196032u    // float pref[512][64] (50 used)
#define OFF_EMBB  1327104u    // bf16 emb [50000][64] (one 128B line per row)
#define WS_NEED   (OFF_EMBB + 6400000u)

__device__ __forceinline__ unsigned short f2bf(float f) {
    unsigned int u = __float_as_uint(f);
    u += 0x7FFFu + ((u >> 16) & 1u);          // round-to-nearest-even
    return (unsigned short)(u >> 16);
}

#define MFMA16(a, b, c) __builtin_amdgcn_mfma_f32_16x16x32_bf16((a), (b), (c), 0, 0, 0)

// ---------------- prep_convert: weights->fragment-order bf16, pos-prefix, emb
// (unchanged from round 9)
__global__ __launch_bounds__(256) void prep_convert(
    const float* __restrict__ W1, const float* __restrict__ W2,
    const float* __restrict__ W3, const float* __restrict__ Wf,
    const float* __restrict__ post, const int* __restrict__ pos,
    const float* __restrict__ emb,
    unsigned short* __restrict__ ws, float* __restrict__ pref, int do_emb)
{
    const int bid = blockIdx.x;
    const int tid = threadIdx.x;

    if (bid < 152) {                      // ---- weight convert, 64x64 (k,n) tile
        __shared__ float tile[64][65];
        const float* src; unsigned short* dst;
        int k0, n0, Ksrc, Nsrc, ksTot, nTiles;
        if (bid < 64)       { src=W2; dst=ws+OFF_WF2/2; k0=(bid>>3)*64; n0=(bid&7)*64; Ksrc=512; Nsrc=512; ksTot=16; nTiles=4; }
        else if (bid < 128) { int b=bid-64;  src=W3; dst=ws+OFF_WF3/2; k0=(b>>3)*64; n0=(b&7)*64; Ksrc=512; Nsrc=512; ksTot=16; nTiles=4; }
        else if (bid < 144) { int b=bid-128; src=W1; dst=ws+OFF_WF1/2; k0=(b>>3)*64; n0=(b&7)*64; Ksrc=100; Nsrc=512; ksTot=4;  nTiles=4; }
        else                { int b=bid-144; src=Wf; dst=ws+OFF_WFF/2; k0=b*64;      n0=0;        Ksrc=512; Nsrc=2;   ksTot=16; nTiles=1; }

        const int c  = tid & 63;
        const int r4 = tid >> 6;
#pragma unroll
        for (int rr = 0; rr < 16; ++rr) {
            int r = rr*4 + r4;
            float v = 0.f;
            if (k0 + r < Ksrc && n0 + c < Nsrc) v = src[(size_t)(k0+r)*Nsrc + n0 + c];
            tile[r][c] = v;
        }
        __syncthreads();
        const int nWords = nTiles * 2 * 64;
        for (int w = tid; w < nWords; w += 256) {
            int lane = w & 63, ks_l = (w >> 6) & 1, nt_l = w >> 7;
            int kr = ks_l*32 + ((lane >> 4) << 3);
            int nc = nt_l*16 + (lane & 15);
            uint4 wv;
            wv.x = (unsigned)f2bf(tile[kr+0][nc]) | ((unsigned)f2bf(tile[kr+1][nc]) << 16);
            wv.y = (unsigned)f2bf(tile[kr+2][nc]) | ((unsigned)f2bf(tile[kr+3][nc]) << 16);
            wv.z = (unsigned)f2bf(tile[kr+4][nc]) | ((unsigned)f2bf(tile[kr+5][nc]) << 16);
            wv.w = (unsigned)f2bf(tile[kr+6][nc]) | ((unsigned)f2bf(tile[kr+7][nc]) << 16);
            int ntile = (n0 >> 4) + nt_l, ks = (k0 >> 5) + ks_l;
            ((uint4*)dst)[(size_t)(ntile*ksTot + ks)*64 + lane] = wv;
        }
    } else if (bid == 152) {              // ---- pos-prefix, 4 chunks x 128, batch-8
        __shared__ int   idx_s[512];
        __shared__ float csum[4][52];
        idx_s[tid]       = pos[tid];
        idx_s[tid + 256] = pos[tid + 256];
        __syncthreads();
        const int c = tid >> 6, d = tid & 63;
        if (d < 50) {
            float run = 0.f;
            for (int b8 = 0; b8 < 16; ++b8) {
                float t[8];
#pragma unroll
                for (int u = 0; u < 8; ++u)
                    t[u] = post[(size_t)idx_s[c*128 + b8*8 + u]*50 + d];
#pragma unroll
                for (int u = 0; u < 8; ++u) {
                    run += t[u];
                    pref[(size_t)(c*128 + b8*8 + u)*64 + d] = run;
                }
            }
            csum[c][d] = run;
        }
        __syncthreads();
        if (d < 50 && c > 0) {
            float off = 0.f;
            for (int cc = 0; cc < c; ++cc) off += csum[cc][d];
            for (int b8 = 0; b8 < 16; ++b8) {
                float t[8];
#pragma unroll
                for (int u = 0; u < 8; ++u)
                    t[u] = pref[(size_t)(c*128 + b8*8 + u)*64 + d];
#pragma unroll
                for (int u = 0; u < 8; ++u)
                    pref[(size_t)(c*128 + b8*8 + u)*64 + d] = t[u] + off;
            }
        }
    } else {                              // ---- emb fp32 -> bf16, coalesced float2, ILP-8
        if (!do_emb) return;
        unsigned* embw = (unsigned*)(ws + OFF_EMBB/2);
        const float2* e2 = (const float2*)emb;        // 1,250,000 float2; never crosses a row
        const unsigned q0 = (unsigned)(bid - 153) * 2048u + (unsigned)tid;
        float2 v[8];
#pragma unroll
        for (int u = 0; u < 8; ++u) {
            unsigned q = q0 + (unsigned)u*256u;
            v[u] = (q < 1250000u) ? e2[q] : (float2){0.f, 0.f};
        }
#pragma unroll
        for (int u = 0; u < 8; ++u) {
            unsigned q = q0 + (unsigned)u*256u;
            if (q < 1250000u) {
                unsigned r = q / 25u, c2 = q - r*25u;
                embw[(size_t)r*32u + c2] =
                    (unsigned)f2bf(v[u].x) | ((unsigned)f2bf(v[u].y) << 16);
            }
        }
    }
}

// ---------------- pooling gather helpers -------------------------------------
__device__ __forceinline__ void acc_u32x4(float (&a)[8], u32x4 q) {
#pragma unroll
    for (int v = 0; v < 4; ++v) {
        a[2*v]   += __uint_as_float(q[v] << 16);
        a[2*v+1] += __uint_as_float(q[v] & 0xffff0000u);
    }
}

// one batch of 64 tokens: 8 nontemporal 16B gathers per lane, exec-masked
// past L (returns zeros) so no serial tail loop is needed.
__device__ __forceinline__ void loadbatch(u32x4 (&q)[8], const u32x4* tbl,
    const unsigned short* idxr, int s0, int L, int tg, int dq)
{
#pragma unroll
    for (int u = 0; u < 8; ++u) {
        int s_ = s0 + u*8 + tg;
        u32x4 v = {0u, 0u, 0u, 0u};
        if (s_ < L)
            v = __builtin_nontemporal_load(&tbl[(size_t)idxr[s_]*8u + (unsigned)dq]);
        q[u] = v;
    }
}

// ---------------- MFMA helpers (swizzled LDS h-tiles, verified r2-r9) --------
__device__ __forceinline__ void load_afrags(bf16x8 (&a)[16],
    const unsigned short* h, int row, int kq)
{
#pragma unroll
    for (int ks = 0; ks < 16; ++ks)
        a[ks] = *(const bf16x8*)((const char*)h +
                  (((unsigned)(row * 1024 + ks * 64 + kq * 16)) ^ ((row & 7) << 4)));
}

__device__ __forceinline__ void store_h(unsigned short* h, const f32x4 (&acc)[4],
    const float (&bb)[4], int wave, int row, int kq)
{
#pragma unroll
    for (int nt = 0; nt < 4; ++nt) {
        int c = wave*64 + nt*16 + row;
#pragma unroll
        for (int r4 = 0; r4 < 4; ++r4) {
            int hrow = kq*4 + r4;
            unsigned base = hrow * 1024;
            *(unsigned short*)((char*)h + ((base + c*2) ^ ((hrow & 7) << 4))) =
                f2bf(fmaxf(acc[nt][r4] + bb[nt], 0.f));
        }
    }
}

// one 512x512 layer: wave owns ntiles wave*4..+3; coalesced fragment loads,
// double-buffered bv arrays, no barriers inside. (VGPR-heavy by design —
// launch_bounds must allow 256 VGPR for the prefetch arrays to stay live.)
__device__ __forceinline__ void layer512(
    const bf16x8 (&a)[16], const unsigned short* __restrict__ Wfrag,
    const float* __restrict__ bias, unsigned short* hout,
    int wave, int row, int kq, int lane)
{
    const bf16x8* bp = (const bf16x8*)Wfrag + ((size_t)(wave*4) * 16 * 64) + lane;
    float bb[4];
#pragma unroll
    for (int nt = 0; nt < 4; ++nt) bb[nt] = bias[wave*64 + nt*16 + row];

    bf16x8 bvA[16], bvB[16];
#pragma unroll
    for (int ks = 0; ks < 16; ++ks) bvA[ks] = bp[(0*16 + ks)*64];
#pragma unroll
    for (int ks = 0; ks < 16; ++ks) bvB[ks] = bp[(1*16 + ks)*64];

    f32x4 acc[4];
    acc[0] = (f32x4){0.f,0.f,0.f,0.f};
#pragma unroll
    for (int ks = 0; ks < 16; ++ks) acc[0] = MFMA16(a[ks], bvA[ks], acc[0]);
#pragma unroll
    for (int ks = 0; ks < 16; ++ks) bvA[ks] = bp[(2*16 + ks)*64];

    acc[1] = (f32x4){0.f,0.f,0.f,0.f};
#pragma unroll
    for (int ks = 0; ks < 16; ++ks) acc[1] = MFMA16(a[ks], bvB[ks], acc[1]);
#pragma unroll
    for (int ks = 0; ks < 16; ++ks) bvB[ks] = bp[(3*16 + ks)*64];

    acc[2] = (f32x4){0.f,0.f,0.f,0.f};
#pragma unroll
    for (int ks = 0; ks < 16; ++ks) acc[2] = MFMA16(a[ks], bvA[ks], acc[2]);
    acc[3] = (f32x4){0.f,0.f,0.f,0.f};
#pragma unroll
    for (int ks = 0; ks < 16; ++ks) acc[3] = MFMA16(a[ks], bvB[ks], acc[3]);

    store_h(hout, acc, bb, wave, row, kq);
}

// ---------------- dan_fused: pooling + 4-layer MFMA MLP ----------------------
// 256 blocks (1/CU) x 512 threads. NOTE: no min-waves bound -> up to 256 VGPR,
// so the 16-deep gather rotation and 32-entry bv prefetch stay in registers.
template<int EMODE>     // 0 = padded bf16 table in ws, 1 = fallback fp32
__global__ __launch_bounds__(512) void dan_fused(
    const float* __restrict__ emb, const int* __restrict__ seq,
    const int* __restrict__ seqlen, const unsigned short* __restrict__ ws_ro,
    const float* __restrict__ pref,
    const float* __restrict__ b1, const float* __restrict__ b2,
    const float* __restrict__ b3, const float* __restrict__ bfin,
    float* __restrict__ out)
{
    __shared__ __align__(16) unsigned short idx_s[8*512];     // 8 KB
    __shared__ __align__(16) unsigned short pooled_s[16*144]; // 4.6 KB
    __shared__ __align__(16) unsigned short hA[8192];         // 16 KB
    __shared__ __align__(16) unsigned short hB[8192];         // 16 KB

    const int tid  = threadIdx.x;
    const int wave = tid >> 6;
    const int lane = tid & 63;
    const int row  = lane & 15;
    const int kq   = lane >> 4;
    const int b0   = blockIdx.x * 8;

    const unsigned short* WF1 = ws_ro + OFF_WF1 / 2;
    const unsigned short* WF2 = ws_ro + OFF_WF2 / 2;
    const unsigned short* WF3 = ws_ro + OFF_WF3 / 2;
    const unsigned short* WFF = ws_ro + OFF_WFF / 2;

    for (int i = tid; i < 8*512; i += 512)
        idx_s[i] = (unsigned short)seq[(size_t)b0 * S_ + i];
    for (int i = tid; i < 16*144; i += 512) pooled_s[i] = 0;

    // W1 fragments: 16 coalesced 16B loads per wave (hide behind pooling)
    bf16x8 w1f[4][4];
    {
        const bf16x8* bp1 = (const bf16x8*)WF1 + ((size_t)(wave*4) * 4 * 64) + lane;
#pragma unroll
        for (int ci = 0; ci < 4; ++ci)
#pragma unroll
            for (int ks = 0; ks < 4; ++ks) w1f[ci][ks] = bp1[(ci*4 + ks)*64];
    }
    __syncthreads();

    // ---- pooling
    const int L = seqlen[b0 + wave];
    const float Lf = (float)L;
    const unsigned short* idxr = idx_s + wave * 512;

    if (EMODE == 0) {
        const int tg = lane >> 3, dq = lane & 7;      // token slot / 16B chunk
        const u32x4* tbl = (const u32x4*)(ws_ro + OFF_EMBB / 2);
        float acc8[8];
#pragma unroll
        for (int j = 0; j < 8; ++j) acc8[j] = 0.f;

        u32x4 qA[8], qB[8];
        loadbatch(qA, tbl, idxr, 0,  L, tg, dq);
        loadbatch(qB, tbl, idxr, 64, L, tg, dq);
        int nit = (L + 63) >> 6;
        nit = (nit + 1) & ~1;                         // even -> static A/B pairing
        for (int i = 0; i < nit; i += 2) {
#pragma unroll
            for (int u = 0; u < 8; ++u) acc_u32x4(acc8, qA[u]);
            loadbatch(qA, tbl, idxr, (i + 2) * 64, L, tg, dq);
#pragma unroll
            for (int u = 0; u < 8; ++u) acc_u32x4(acc8, qB[u]);
            loadbatch(qB, tbl, idxr, (i + 3) * 64, L, tg, dq);
        }
#pragma unroll
        for (int j = 0; j < 8; ++j) acc8[j] += __shfl_xor(acc8[j], 8);
#pragma unroll
        for (int j = 0; j < 8; ++j) acc8[j] += __shfl_xor(acc8[j], 16);
#pragma unroll
        for (int j = 0; j < 8; ++j) acc8[j] += __shfl_xor(acc8[j], 32);
        if (lane < 8) {
#pragma unroll
            for (int j = 0; j < 8; ++j) {
                int d = lane*8 + j;
                if (d < 50) pooled_s[wave*144 + d] = f2bf(acc8[j] / Lf);
            }
        }
    } else {
        float accE = 0.f;
        for (int s = 0; s < L; ++s) {
            int tok = idxr[s];
            if (lane < 50) accE += emb[(size_t)tok*50 + lane];
        }
        if (lane < 50) pooled_s[wave*144 + lane] = f2bf(accE / Lf);
    }
    if (lane < 50)
        pooled_s[wave*144 + 50 + lane] = f2bf(pref[(size_t)(L-1)*64 + lane] / Lf);
    __syncthreads();

    // ---- Layer 1 (K=128) from pooled_s, weights in regs
    {
        bf16x8 a1[4];
#pragma unroll
        for (int ks = 0; ks < 4; ++ks)
            a1[ks] = *(const bf16x8*)&pooled_s[row*144 + ks*32 + kq*8];
        f32x4 acc[4];
        float bb[4];
#pragma unroll
        for (int ci = 0; ci < 4; ++ci) {
            bb[ci] = b1[wave*64 + ci*16 + row];
            acc[ci] = (f32x4){0.f,0.f,0.f,0.f};
#pragma unroll
            for (int ks = 0; ks < 4; ++ks) acc[ci] = MFMA16(a1[ks], w1f[ci][ks], acc[ci]);
        }
        store_h(hA, acc, bb, wave, row, kq);
    }
    __syncthreads();

    // ---- Layer 2 (K=512): hA -> hB
    bf16x8 a[16];
    load_afrags(a, hA, row, kq);
    layer512(a, WF2, b2, hB, wave, row, kq, lane);
    __syncthreads();

    // ---- Layer 3 (K=512): hB -> hA
    load_afrags(a, hB, row, kq);
    layer512(a, WF3, b3, hA, wave, row, kq, lane);
    __syncthreads();

    // ---- Final (K=512, N padded 2->16): wave 0 only
    if (wave == 0) {
        load_afrags(a, hA, row, kq);
        const bf16x8* bpf = (const bf16x8*)WFF + lane;
        f32x4 accf = {0.f, 0.f, 0.f, 0.f};
#pragma unroll
        for (int ks = 0; ks < 16; ++ks) {
            bf16x8 bv = bpf[ks*64];
            accf = MFMA16(a[ks], bv, accf);
        }
        if (row < 2 && kq < 2) {
            float bb = bfin[row];
#pragma unroll
            for (int r4 = 0; r4 < 4; ++r4) {
                int m = kq*4 + r4;                   // real rows 0..7
                out[(size_t)(b0 + m) * 2 + row] = accf[r4] + bb;
            }
        }
    }
}

extern "C" void kernel_launch(void* const* d_in, const int* in_sizes, int n_in,
                              void* d_out, int out_size, void* d_ws, size_t ws_size,
                              hipStream_t stream)
{
    const float* emb    = (const float*)d_in[0];
    const float* post   = (const float*)d_in[1];
    const float* W1     = (const float*)d_in[2];
    const float* b1     = (const float*)d_in[3];
    const float* W2     = (const float*)d_in[4];
    const float* b2     = (const float*)d_in[5];
    const float* W3     = (const float*)d_in[6];
    const float* b3     = (const float*)d_in[7];
    const float* Wf     = (const float*)d_in[8];
    const float* bf     = (const float*)d_in[9];
    const int*   seq    = (const int*)d_in[10];
    const int*   seqlen = (const int*)d_in[11];
    const int*   pos    = (const int*)d_in[12];
    float*       out    = (float*)d_out;

    unsigned short* ws = (unsigned short*)d_ws;
    float* pref = (float*)((char*)d_ws + OFF_PREF);
    const int do_emb = (ws_size >= (size_t)WS_NEED) ? 1 : 0;

    const int prep_blocks = do_emb ? (153 + 611) : 153;
    prep_convert<<<prep_blocks, 256, 0, stream>>>(W1, W2, W3, Wf, post, pos, emb,
                                                  ws, pref, do_emb);
    if (do_emb)
        dan_fused<0><<<B_ / 8, 512, 0, stream>>>(emb, seq, seqlen, ws, pref,
                                                 b1, b2, b3, bf, out);
    else
        dan_fused<1><<<B_ / 8, 512, 0, stream>>>(emb, seq, seqlen, ws, pref,
                                                 b1, b2, b3, bf, out);
}